// Round 11
// baseline (208.618 us; speedup 1.0000x reference)
//
#include <hip/hip_runtime.h>
#include <hip/hip_bf16.h>

typedef __bf16 bf16_t;
typedef bf16_t bf16x4 __attribute__((ext_vector_type(4)));
typedef bf16_t bf16x8 __attribute__((ext_vector_type(8)));
typedef float f32x4 __attribute__((ext_vector_type(4)));

constexpr int NB   = 16;
constexpr int NN   = 4096;
constexpr int PD   = 768;    // patch dim (K)
constexpr int HID  = 768;    // hidden (N out)
constexpr int PSZ  = 10240;  // pos table size
constexpr int MT   = NB * NN;        // 65536 rows
constexpr int BM   = 128;
constexpr int BN   = 128;
constexpr int BK   = 32;
constexpr int NT   = PD / BK;        // 24 k-tiles
constexpr int LDSC = 132;            // padded C-slice row stride (floats)
constexpr size_t PVN = (size_t)MT * PD;    // 50331648
constexpr size_t WN  = (size_t)HID * PD;   // 589824

__device__ __forceinline__ bf16x8 cvt8_affine(const float4& x, const float4& y,
                                              float s, float o) {
    bf16x8 r;
    r[0] = (bf16_t)__builtin_fmaf(s, x.x, o);
    r[1] = (bf16_t)__builtin_fmaf(s, x.y, o);
    r[2] = (bf16_t)__builtin_fmaf(s, x.z, o);
    r[3] = (bf16_t)__builtin_fmaf(s, x.w, o);
    r[4] = (bf16_t)__builtin_fmaf(s, y.x, o);
    r[5] = (bf16_t)__builtin_fmaf(s, y.y, o);
    r[6] = (bf16_t)__builtin_fmaf(s, y.z, o);
    r[7] = (bf16_t)__builtin_fmaf(s, y.w, o);
    return r;
}

__device__ __forceinline__ bf16x4 cvt4_affine(const float4& x, float s, float o) {
    bf16x4 r;
    r[0] = (bf16_t)__builtin_fmaf(s, x.x, o);
    r[1] = (bf16_t)__builtin_fmaf(s, x.y, o);
    r[2] = (bf16_t)__builtin_fmaf(s, x.z, o);
    r[3] = (bf16_t)__builtin_fmaf(s, x.w, o);
    return r;
}

// ------- Pass 1a: mask-ballot compaction + cvt + inline zero-fill (round-9) -
__global__ __launch_bounds__(256)
void compact_cvt(const float* __restrict__ pv,
                 const int* __restrict__ mask,
                 const float* __restrict__ W,
                 bf16_t* __restrict__ Ab,
                 bf16_t* __restrict__ Wb,
                 int* __restrict__ rowmap,
                 int* __restrict__ counter,
                 float* __restrict__ out)
{
    const int bid = blockIdx.x;
    const int tid = threadIdx.x;
    if (bid < 1024) {
        __shared__ int ls_slot[64];
        const int rowbase = bid * 64;
        const int lane = tid & 63;
        const int wv   = tid >> 6;
        if (wv == 0) {
            const int mk = mask[rowbase + lane];          // !=0 -> masked
            const unsigned long long b = __ballot(mk == 0);
            const int total = __popcll(b);
            const int pos = __popcll(b & ((1ull << lane) - 1ull));
            int gb = 0;
            if (lane == 0) gb = atomicAdd(counter, total);
            gb = __shfl(gb, 0);
            const int slot = (mk == 0) ? (gb + pos) : -1;
            ls_slot[lane] = slot;
            if (slot >= 0) rowmap[slot] = rowbase + lane;
        }
        __syncthreads();
        for (int i = wv; i < 64; i += 4) {
            const int slot = ls_slot[i];
            const int grow = rowbase + i;
            if (slot >= 0) {
                const float* src = pv + (size_t)grow * PD + lane * 12;
                bf16_t* dst = Ab + (size_t)slot * PD + lane * 12;
                #pragma unroll
                for (int q = 0; q < 3; ++q) {
                    const float4 v = *(const float4*)(src + q * 4);
                    *(bf16x4*)(dst + q * 4) = cvt4_affine(v, 2.f, -1.f);
                }
            } else {
                float* dst = out + (size_t)grow * HID + lane * 12;
                const float4 z{0.f, 0.f, 0.f, 0.f};
                #pragma unroll
                for (int q = 0; q < 3; ++q)
                    *(float4*)(dst + q * 4) = z;
            }
        }
    } else {
        const size_t nu = WN / 8;
        for (size_t u = (size_t)(bid - 1024) * 256 + tid; u < nu;
             u += (size_t)64 * 256) {
            const float4 x = ((const float4*)W)[2 * u];
            const float4 y = ((const float4*)W)[2 * u + 1];
            *(bf16x8*)(Wb + 8 * u) = cvt8_affine(x, y, 1.f, 0.f);
        }
    }
}

// ------- Pass 1b (non-compacting fallback): plain fp32->bf16 convert --------
__global__ __launch_bounds__(256)
void cvt_kernel(const float* __restrict__ pv, const float* __restrict__ W,
                bf16_t* __restrict__ Ab, bf16_t* __restrict__ Wb)
{
    const size_t nunits = (PVN + WN) / 8;
    const size_t stride = (size_t)gridDim.x * blockDim.x;
    for (size_t u = (size_t)blockIdx.x * blockDim.x + threadIdx.x;
         u < nunits; u += stride) {
        if (u < PVN / 8) {
            const float4 x = ((const float4*)pv)[2 * u];
            const float4 y = ((const float4*)pv)[2 * u + 1];
            *(bf16x8*)(Ab + 8 * u) = cvt8_affine(x, y, 2.f, -1.f);
        } else {
            const size_t v = u - PVN / 8;
            const float4 x = ((const float4*)W)[2 * v];
            const float4 y = ((const float4*)W)[2 * v + 1];
            *(bf16x8*)(Wb + 8 * v) = cvt8_affine(x, y, 1.f, 0.f);
        }
    }
}

// ------- Pass 2: bf16 MFMA GEMM, B-only LDS staging, A direct-to-register ---
__device__ __forceinline__ void gload16(const void* g, void* l) {
    __builtin_amdgcn_global_load_lds(
        (const __attribute__((address_space(1))) void*)g,
        (__attribute__((address_space(3))) void*)l, 16, 0, 0);
}

template <bool USE_MAP>
__global__ __launch_bounds__(256, 4)
void gemm_kernel(const bf16_t* __restrict__ Ab,
                 const bf16_t* __restrict__ Wb,
                 const int* __restrict__ posids,
                 const int* __restrict__ mask,
                 const float* __restrict__ ptab,
                 float* __restrict__ out,
                 const int* __restrict__ rowmap,
                 const int* __restrict__ counter)
{
    // LDS: B double-buffer (2 x 8KB); epilogue reuses as float Cs[32][LDSC].
    __shared__ alignas(16) unsigned char smem[32 * LDSC * 4];   // 16896 B
    bf16_t* const Bsb = (bf16_t*)smem;                 // [2][BN*BK]
    float*  const Cs  = (float*)smem;                  // [32][LDSC]

    int Mc = MT;
    int mt, nt;
    const int bid = blockIdx.x;
    if constexpr (USE_MAP) {
        Mc = counter[0];
        const int Mtiles = (Mc + BM - 1) / BM;
        const int nact = Mtiles * 6;
        if (bid >= nact) return;      // exits round-robin across XCDs
        // Dynamic bijective XCD swizzle over the ACTIVE block count.
        const int q = nact >> 3, rm = nact & 7;
        const int x = bid & 7, i = bid >> 3;
        const int logical = (x < rm ? x * (q + 1) : rm * (q + 1) + (x - rm) * q) + i;
        mt = logical / 6;
        nt = logical - mt * 6;
    } else {
        const int nwg = gridDim.x;
        const int cpx = nwg >> 3;
        const int logical = (bid & 7) * cpx + (bid >> 3);
        mt = logical / 6;
        nt = logical - mt * 6;
    }
    const int row0 = mt * BM;
    const int col0 = nt * BN;

    const int tid  = threadIdx.x;
    const int lane = tid & 63;
    const int wid  = tid >> 6;
    const int wm   = wid >> 1;
    const int wn   = wid & 1;

    // B staging: thread t owns one 16B slot; LDS lane-linear
    const int srow = tid >> 2;          // 0..63
    const int sk   = (tid & 3) * 8;     // 0,8,16,24
    const bf16_t* b0 = Wb + (size_t)(col0 + srow) * PD + sk;
    const int lds_lo = srow * BK + sk;
    const int lds_hi = (srow + 64) * BK + sk;

    f32x4 acc[4][4];
    #pragma unroll
    for (int i = 0; i < 4; ++i)
        #pragma unroll
        for (int j = 0; j < 4; ++j)
            acc[i][j] = f32x4{0.f, 0.f, 0.f, 0.f};

    const int lr = lane & 15;
    const int kg = lane >> 4;
    const int b_rd_off = (wn * 64 + lr) * BK + kg * 8;

    // A fragment base pointers: 16B contiguous per lane, full-line coalesced
    const bf16_t* aF[4];
    #pragma unroll
    for (int i = 0; i < 4; ++i)
        aF[i] = Ab + (size_t)(row0 + wm * 64 + i * 16 + lr) * PD + kg * 8;

    // prologue: stage B tile 0 into buf 0
    gload16(b0,           Bsb + lds_lo);
    gload16(b0 + 64 * PD, Bsb + lds_hi);
    __syncthreads();

    int cur = 0;
    for (int t = 0; t < NT; ++t) {
        // A frags for this K-tile: issue first (older than B stage in vmcnt)
        bf16x8 af[4];
        #pragma unroll
        for (int i = 0; i < 4; ++i)
            af[i] = *(const bf16x8*)(aF[i] + t * BK);

        if (t + 1 < NT) {
            const int k1 = (t + 1) * BK;
            const int nb = cur ^ 1;
            gload16(b0 + k1,           Bsb + nb * (BN * BK) + lds_lo);
            gload16(b0 + 64 * PD + k1, Bsb + nb * (BN * BK) + lds_hi);
        }

        bf16x8 bfv[4];
        #pragma unroll
        for (int i = 0; i < 4; ++i)
            bfv[i] = *(const bf16x8*)(Bsb + cur * (BN * BK) + b_rd_off + i * 16 * BK);

        #pragma unroll
        for (int i = 0; i < 4; ++i)
            #pragma unroll
            for (int j = 0; j < 4; ++j)
                acc[i][j] = __builtin_amdgcn_mfma_f32_16x16x32_bf16(
                    af[i], bfv[j], acc[i][j], 0, 0, 0);

        __syncthreads();
        cur ^= 1;
    }

    // ---- Epilogue: LDS-transposed, vectorized; row metadata hoisted ----
    const int lrow_w  = wm * 16 + kg * 4;
    const int lcol_w  = wn * 64 + lr;
    const int rr = tid >> 3;                  // 0..31
    const int cg = tid & 7;                   // 0..7
    const int erow_local = (rr & 15) + (rr >> 4) * 64;

    int grow4[4], p04[4], p14[4];
    #pragma unroll
    for (int mi = 0; mi < 4; ++mi) {
        int crow = row0 + mi * 16 + erow_local;
        if constexpr (USE_MAP) {
            const int cc = crow < Mc ? crow : Mc - 1;   // clamped (store guarded)
            grow4[mi] = rowmap[cc];
        } else {
            grow4[mi] = crow;
        }
        int p0 = posids[2 * grow4[mi]];
        int p1 = posids[2 * grow4[mi] + 1];
        p04[mi] = p0 < 0 ? 0 : p0;
        p14[mi] = p1 < 0 ? 0 : p1;
    }

    #pragma unroll
    for (int mi = 0; mi < 4; ++mi) {
        __syncthreads();                      // staging/prev-slice reads done
        #pragma unroll
        for (int r = 0; r < 4; ++r)
            #pragma unroll
            for (int ni = 0; ni < 4; ++ni)
                Cs[(lrow_w + r) * LDSC + lcol_w + ni * 16] = acc[mi][ni][r];
        __syncthreads();                      // slice visible

        const int crow = row0 + mi * 16 + erow_local;
        if constexpr (USE_MAP) {
            if (crow >= Mc) continue;
            const float* t0 = ptab + (size_t)p04[mi] * HID + col0;
            const float* t1 = ptab + (size_t)PSZ * HID + (size_t)p14[mi] * HID + col0;
            float* orow = out + (size_t)grow4[mi] * HID + col0;
            #pragma unroll
            for (int j = 0; j < 4; ++j) {
                const int c = (cg + 8 * j) * 4;
                float4 v  = *(const float4*)&Cs[rr * LDSC + c];
                const float4 e0 = *(const float4*)(t0 + c);
                const float4 e1 = *(const float4*)(t1 + c);
                v.x += e0.x + e1.x;
                v.y += e0.y + e1.y;
                v.z += e0.z + e1.z;
                v.w += e0.w + e1.w;
                *(float4*)(orow + c) = v;
            }
        } else {
            const int grow = crow;
            float* orow = out + (size_t)grow * HID + col0;
            const int mk = mask[grow];
            if (mk) {
                const float4 z{0.f, 0.f, 0.f, 0.f};
                #pragma unroll
                for (int j = 0; j < 4; ++j)
                    *(float4*)(orow + (cg + 8 * j) * 4) = z;
            } else {
                const float* t0 = ptab + (size_t)p04[mi] * HID + col0;
                const float* t1 = ptab + (size_t)PSZ * HID + (size_t)p14[mi] * HID + col0;
                #pragma unroll
                for (int j = 0; j < 4; ++j) {
                    const int c = (cg + 8 * j) * 4;
                    float4 v  = *(const float4*)&Cs[rr * LDSC + c];
                    const float4 e0 = *(const float4*)(t0 + c);
                    const float4 e1 = *(const float4*)(t1 + c);
                    v.x += e0.x + e1.x;
                    v.y += e0.y + e1.y;
                    v.z += e0.z + e1.z;
                    v.w += e0.w + e1.w;
                    *(float4*)(orow + c) = v;
                }
            }
        }
    }
}

// ---------------- Fallback (fused kernel, used if ws too small) -------------
constexpr int LDSS = 40;

__global__ __launch_bounds__(256, 2)
void vpe_kernel(const float* __restrict__ pv,
                const int* __restrict__ posids,
                const int* __restrict__ mask,
                const float* __restrict__ W,
                const float* __restrict__ ptab,
                float* __restrict__ out)
{
    __shared__ alignas(16) bf16_t As[2][BM * LDSS];
    __shared__ alignas(16) bf16_t Bs[2][BM * LDSS];

    const int nwg = gridDim.x;
    const int cpx = nwg >> 3;
    const int logical = (blockIdx.x & 7) * cpx + (blockIdx.x >> 3);
    const int mt = logical / 6;
    const int nt = logical - mt * 6;
    const int row0 = mt * BM;
    const int col0 = nt * BN;

    const int tid  = threadIdx.x;
    const int lane = tid & 63;
    const int wid  = tid >> 6;
    const int wm   = wid >> 1;
    const int wn   = wid & 1;
    const int srow = tid >> 1;
    const int scol = (tid & 1) << 4;

    const float* aptr = pv + (size_t)(row0 + srow) * PD + scol;
    const float* bptr = W  + (size_t)(col0 + srow) * PD + scol;
    const int lds_w_off = srow * LDSS + scol;

    f32x4 acc[4][4];
    #pragma unroll
    for (int i = 0; i < 4; ++i)
        #pragma unroll
        for (int j = 0; j < 4; ++j)
            acc[i][j] = f32x4{0.f, 0.f, 0.f, 0.f};

    const int lr = lane & 15;
    const int kg = lane >> 4;
    const int a_rd_off = (wm * 64 + lr) * LDSS + kg * 8;
    const int b_rd_off = (wn * 64 + lr) * LDSS + kg * 8;

    float4 ra[4], rb[4];
    #pragma unroll
    for (int q = 0; q < 4; ++q) {
        ra[q] = *(const float4*)(aptr + q * 4);
        rb[q] = *(const float4*)(bptr + q * 4);
    }
    {
        bf16x8 av0 = cvt8_affine(ra[0], ra[1], 2.f, -1.f);
        bf16x8 av1 = cvt8_affine(ra[2], ra[3], 2.f, -1.f);
        bf16x8 bv0 = cvt8_affine(rb[0], rb[1], 1.f, 0.f);
        bf16x8 bv1 = cvt8_affine(rb[2], rb[3], 1.f, 0.f);
        *(bf16x8*)(&As[0][lds_w_off])     = av0;
        *(bf16x8*)(&As[0][lds_w_off] + 8) = av1;
        *(bf16x8*)(&Bs[0][lds_w_off])     = bv0;
        *(bf16x8*)(&Bs[0][lds_w_off] + 8) = bv1;
    }
    __syncthreads();

    int cur = 0;
    for (int t = 0; t < NT - 1; ++t) {
        const int k1 = (t + 1) * BK;
        #pragma unroll
        for (int q = 0; q < 4; ++q) {
            ra[q] = *(const float4*)(aptr + k1 + q * 4);
            rb[q] = *(const float4*)(bptr + k1 + q * 4);
        }
        bf16x8 af[4], bfv[4];
        #pragma unroll
        for (int i = 0; i < 4; ++i) {
            af[i]  = *(const bf16x8*)(&As[cur][a_rd_off] + i * 16 * LDSS);
            bfv[i] = *(const bf16x8*)(&Bs[cur][b_rd_off] + i * 16 * LDSS);
        }
        #pragma unroll
        for (int i = 0; i < 4; ++i)
            #pragma unroll
            for (int j = 0; j < 4; ++j)
                acc[i][j] = __builtin_amdgcn_mfma_f32_16x16x32_bf16(
                    af[i], bfv[j], acc[i][j], 0, 0, 0);
        {
            bf16x8 av0 = cvt8_affine(ra[0], ra[1], 2.f, -1.f);
            bf16x8 av1 = cvt8_affine(ra[2], ra[3], 2.f, -1.f);
            bf16x8 bv0 = cvt8_affine(rb[0], rb[1], 1.f, 0.f);
            bf16x8 bv1 = cvt8_affine(rb[2], rb[3], 1.f, 0.f);
            const int nb = cur ^ 1;
            *(bf16x8*)(&As[nb][lds_w_off])     = av0;
            *(bf16x8*)(&As[nb][lds_w_off] + 8) = av1;
            *(bf16x8*)(&Bs[nb][lds_w_off])     = bv0;
            *(bf16x8*)(&Bs[nb][lds_w_off] + 8) = bv1;
        }
        __syncthreads();
        cur ^= 1;
    }
    {
        bf16x8 af[4], bfv[4];
        #pragma unroll
        for (int i = 0; i < 4; ++i) {
            af[i]  = *(const bf16x8*)(&As[cur][a_rd_off] + i * 16 * LDSS);
            bfv[i] = *(const bf16x8*)(&Bs[cur][b_rd_off] + i * 16 * LDSS);
        }
        #pragma unroll
        for (int i = 0; i < 4; ++i)
            #pragma unroll
            for (int j = 0; j < 4; ++j)
                acc[i][j] = __builtin_amdgcn_mfma_f32_16x16x32_bf16(
                    af[i], bfv[j], acc[i][j], 0, 0, 0);
    }
    #pragma unroll
    for (int mi = 0; mi < 4; ++mi) {
        #pragma unroll
        for (int r = 0; r < 4; ++r) {
            const int grow = row0 + wm * 64 + mi * 16 + kg * 4 + r;
            const int mk = mask[grow];
            int p0 = posids[2 * grow];
            int p1 = posids[2 * grow + 1];
            p0 = p0 < 0 ? 0 : p0;
            p1 = p1 < 0 ? 0 : p1;
            const float* t0 = ptab + (size_t)p0 * HID;
            const float* t1 = ptab + (size_t)PSZ * HID + (size_t)p1 * HID;
            float* orow = out + (size_t)grow * HID;
            #pragma unroll
            for (int ni = 0; ni < 4; ++ni) {
                const int col = col0 + wn * 64 + ni * 16 + lr;
                const float v = acc[mi][ni][r] + t0[col] + t1[col];
                orow[col] = mk ? 0.f : v;
            }
        }
    }
}

extern "C" void kernel_launch(void* const* d_in, const int* in_sizes, int n_in,
                              void* d_out, int out_size, void* d_ws, size_t ws_size,
                              hipStream_t stream) {
    (void)in_sizes; (void)n_in; (void)out_size;
    const float* pv     = (const float*)d_in[0];
    const int*   posids = (const int*)d_in[1];
    const int*   mask   = (const int*)d_in[2];
    const float* W      = (const float*)d_in[3];
    const float* ptab   = (const float*)d_in[4];
    float*       out    = (float*)d_out;

    const size_t AB_B = PVN * sizeof(bf16_t);   // 96 MB
    const size_t WB_B = WN * sizeof(bf16_t);    // 1.125 MB
    const size_t RM_B = (size_t)MT * 4;         // 256 KB
    const size_t need1 = AB_B + WB_B;
    const size_t need2 = AB_B + WB_B + RM_B + 16;
    const int grid = (MT / BM) * (HID / BN);    // 3072

    if (ws_size >= need2) {
        bf16_t* Ab   = (bf16_t*)d_ws;
        bf16_t* Wb   = Ab + PVN;
        int* rowmap  = (int*)((char*)d_ws + AB_B + WB_B);
        int* counter = (int*)((char*)d_ws + AB_B + WB_B + RM_B);
        hipMemsetAsync(counter, 0, 16, stream);
        hipLaunchKernelGGL(compact_cvt, dim3(1088), dim3(256), 0, stream,
                           pv, mask, W, Ab, Wb, rowmap, counter, out);
        hipLaunchKernelGGL((gemm_kernel<true>), dim3(grid), dim3(256), 0, stream,
                           Ab, Wb, posids, mask, ptab, out, rowmap, counter);
    } else if (ws_size >= need1) {
        bf16_t* Ab = (bf16_t*)d_ws;
        bf16_t* Wb = Ab + PVN;
        hipLaunchKernelGGL(cvt_kernel, dim3(2048), dim3(256), 0, stream,
                           pv, W, Ab, Wb);
        hipLaunchKernelGGL((gemm_kernel<false>), dim3(grid), dim3(256), 0, stream,
                           Ab, Wb, posids, mask, ptab, out, nullptr, nullptr);
    } else {
        hipLaunchKernelGGL(vpe_kernel, dim3(grid), dim3(256), 0, stream,
                           pv, posids, mask, W, ptab, out);
    }
}

// Round 13
// 205.717 us; speedup vs baseline: 1.0141x; 1.0141x over previous
//
#include <hip/hip_runtime.h>
#include <hip/hip_bf16.h>

typedef __bf16 bf16_t;
typedef bf16_t bf16x4 __attribute__((ext_vector_type(4)));
typedef bf16_t bf16x8 __attribute__((ext_vector_type(8)));
typedef float f32x4 __attribute__((ext_vector_type(4)));

constexpr int NB   = 16;
constexpr int NN   = 4096;
constexpr int PD   = 768;    // patch dim (K)
constexpr int HID  = 768;    // hidden (N out)
constexpr int PSZ  = 10240;  // pos table size
constexpr int MT   = NB * NN;        // 65536 rows
constexpr int BM   = 128;
constexpr int BN   = 128;
constexpr int BK   = 32;
constexpr int NT   = PD / BK;        // 24 k-tiles (even -> clean 2x unroll)
constexpr int LDSC = 132;            // padded C-slice row stride (floats)
constexpr size_t PVN = (size_t)MT * PD;    // 50331648
constexpr size_t WN  = (size_t)HID * PD;   // 589824

__device__ __forceinline__ bf16x8 cvt8_affine(const float4& x, const float4& y,
                                              float s, float o) {
    bf16x8 r;
    r[0] = (bf16_t)__builtin_fmaf(s, x.x, o);
    r[1] = (bf16_t)__builtin_fmaf(s, x.y, o);
    r[2] = (bf16_t)__builtin_fmaf(s, x.z, o);
    r[3] = (bf16_t)__builtin_fmaf(s, x.w, o);
    r[4] = (bf16_t)__builtin_fmaf(s, y.x, o);
    r[5] = (bf16_t)__builtin_fmaf(s, y.y, o);
    r[6] = (bf16_t)__builtin_fmaf(s, y.z, o);
    r[7] = (bf16_t)__builtin_fmaf(s, y.w, o);
    return r;
}

__device__ __forceinline__ bf16x4 cvt4_affine(const float4& x, float s, float o) {
    bf16x4 r;
    r[0] = (bf16_t)__builtin_fmaf(s, x.x, o);
    r[1] = (bf16_t)__builtin_fmaf(s, x.y, o);
    r[2] = (bf16_t)__builtin_fmaf(s, x.z, o);
    r[3] = (bf16_t)__builtin_fmaf(s, x.w, o);
    return r;
}

// ------- Pass 1a: mask-ballot compaction + cvt + inline zero-fill (round-9) -
__global__ __launch_bounds__(256)
void compact_cvt(const float* __restrict__ pv,
                 const int* __restrict__ mask,
                 const float* __restrict__ W,
                 bf16_t* __restrict__ Ab,
                 bf16_t* __restrict__ Wb,
                 int* __restrict__ rowmap,
                 int* __restrict__ counter,
                 float* __restrict__ out)
{
    const int bid = blockIdx.x;
    const int tid = threadIdx.x;
    if (bid < 1024) {
        __shared__ int ls_slot[64];
        const int rowbase = bid * 64;
        const int lane = tid & 63;
        const int wv   = tid >> 6;
        if (wv == 0) {
            const int mk = mask[rowbase + lane];          // !=0 -> masked
            const unsigned long long b = __ballot(mk == 0);
            const int total = __popcll(b);
            const int pos = __popcll(b & ((1ull << lane) - 1ull));
            int gb = 0;
            if (lane == 0) gb = atomicAdd(counter, total);
            gb = __shfl(gb, 0);
            const int slot = (mk == 0) ? (gb + pos) : -1;
            ls_slot[lane] = slot;
            if (slot >= 0) rowmap[slot] = rowbase + lane;
        }
        __syncthreads();
        for (int i = wv; i < 64; i += 4) {
            const int slot = ls_slot[i];
            const int grow = rowbase + i;
            if (slot >= 0) {
                const float* src = pv + (size_t)grow * PD + lane * 12;
                bf16_t* dst = Ab + (size_t)slot * PD + lane * 12;
                #pragma unroll
                for (int q = 0; q < 3; ++q) {
                    const float4 v = *(const float4*)(src + q * 4);
                    *(bf16x4*)(dst + q * 4) = cvt4_affine(v, 2.f, -1.f);
                }
            } else {
                float* dst = out + (size_t)grow * HID + lane * 12;
                const float4 z{0.f, 0.f, 0.f, 0.f};
                #pragma unroll
                for (int q = 0; q < 3; ++q)
                    *(float4*)(dst + q * 4) = z;
            }
        }
    } else {
        const size_t nu = WN / 8;
        for (size_t u = (size_t)(bid - 1024) * 256 + tid; u < nu;
             u += (size_t)64 * 256) {
            const float4 x = ((const float4*)W)[2 * u];
            const float4 y = ((const float4*)W)[2 * u + 1];
            *(bf16x8*)(Wb + 8 * u) = cvt8_affine(x, y, 1.f, 0.f);
        }
    }
}

// ------- Pass 1b (non-compacting fallback): plain fp32->bf16 convert --------
__global__ __launch_bounds__(256)
void cvt_kernel(const float* __restrict__ pv, const float* __restrict__ W,
                bf16_t* __restrict__ Ab, bf16_t* __restrict__ Wb)
{
    const size_t nunits = (PVN + WN) / 8;
    const size_t stride = (size_t)gridDim.x * blockDim.x;
    for (size_t u = (size_t)blockIdx.x * blockDim.x + threadIdx.x;
         u < nunits; u += stride) {
        if (u < PVN / 8) {
            const float4 x = ((const float4*)pv)[2 * u];
            const float4 y = ((const float4*)pv)[2 * u + 1];
            *(bf16x8*)(Ab + 8 * u) = cvt8_affine(x, y, 2.f, -1.f);
        } else {
            const size_t v = u - PVN / 8;
            const float4 x = ((const float4*)W)[2 * v];
            const float4 y = ((const float4*)W)[2 * v + 1];
            *(bf16x8*)(Wb + 8 * v) = cvt8_affine(x, y, 1.f, 0.f);
        }
    }
}

// ---- Pass 2: bf16 MFMA GEMM, B-only LDS, A register-prefetch one-ahead ----
__device__ __forceinline__ void gload16(const void* g, void* l) {
    __builtin_amdgcn_global_load_lds(
        (const __attribute__((address_space(1))) void*)g,
        (__attribute__((address_space(3))) void*)l, 16, 0, 0);
}

// One K-step: prefetch A(T+1) into AFN + stage B(T+1); compute with AFC.
#define GSTEP(AFC, AFN, T)                                                     \
    {                                                                          \
        if ((T) + 1 < NT) {                                                    \
            const int k1 = ((T) + 1) * BK;                                     \
            _Pragma("unroll")                                                  \
            for (int i_ = 0; i_ < 4; ++i_)                                     \
                AFN[i_] = *(const bf16x8*)(aF[i_] + k1);                       \
            const int nb_ = cur ^ 1;                                           \
            gload16(b0 + k1,           Bsb + nb_ * (BN * BK) + lds_lo);        \
            gload16(b0 + 64 * PD + k1, Bsb + nb_ * (BN * BK) + lds_hi);        \
        }                                                                      \
        bf16x8 bfv_[4];                                                        \
        _Pragma("unroll")                                                      \
        for (int i_ = 0; i_ < 4; ++i_)                                         \
            bfv_[i_] = *(const bf16x8*)(Bsb + cur * (BN * BK) + b_rd_off +     \
                                        i_ * 16 * BK);                         \
        _Pragma("unroll")                                                      \
        for (int i_ = 0; i_ < 4; ++i_)                                         \
            _Pragma("unroll")                                                  \
            for (int j_ = 0; j_ < 4; ++j_)                                     \
                acc[i_][j_] = __builtin_amdgcn_mfma_f32_16x16x32_bf16(         \
                    AFC[i_], bfv_[j_], acc[i_][j_], 0, 0, 0);                  \
        __syncthreads();                                                       \
        cur ^= 1;                                                              \
    }

template <bool USE_MAP>
__global__ __launch_bounds__(256, 3)
void gemm_kernel(const bf16_t* __restrict__ Ab,
                 const bf16_t* __restrict__ Wb,
                 const int* __restrict__ posids,
                 const int* __restrict__ mask,
                 const float* __restrict__ ptab,
                 float* __restrict__ out,
                 const int* __restrict__ rowmap,
                 const int* __restrict__ counter)
{
    // LDS: B double-buffer (2 x 8KB); epilogue reuses as float Cs[32][LDSC].
    __shared__ alignas(16) unsigned char smem[32 * LDSC * 4];   // 16896 B
    bf16_t* const Bsb = (bf16_t*)smem;                 // [2][BN*BK]
    float*  const Cs  = (float*)smem;                  // [32][LDSC]

    int Mc = MT;
    int mt, nt;
    const int bid = blockIdx.x;
    if constexpr (USE_MAP) {
        Mc = counter[0];
        const int Mtiles = (Mc + BM - 1) / BM;
        const int nact = Mtiles * 6;
        if (bid >= nact) return;      // exits round-robin across XCDs
        // Dynamic bijective XCD swizzle over the ACTIVE block count.
        const int q = nact >> 3, rm = nact & 7;
        const int x = bid & 7, i = bid >> 3;
        const int logical = (x < rm ? x * (q + 1) : rm * (q + 1) + (x - rm) * q) + i;
        mt = logical / 6;
        nt = logical - mt * 6;
    } else {
        const int nwg = gridDim.x;
        const int cpx = nwg >> 3;
        const int logical = (bid & 7) * cpx + (bid >> 3);
        mt = logical / 6;
        nt = logical - mt * 6;
    }
    const int row0 = mt * BM;
    const int col0 = nt * BN;

    const int tid  = threadIdx.x;
    const int lane = tid & 63;
    const int wid  = tid >> 6;
    const int wm   = wid >> 1;
    const int wn   = wid & 1;

    // B staging: thread t owns one 16B slot; LDS lane-linear
    const int srow = tid >> 2;          // 0..63
    const int sk   = (tid & 3) * 8;     // 0,8,16,24
    const bf16_t* b0 = Wb + (size_t)(col0 + srow) * PD + sk;
    const int lds_lo = srow * BK + sk;
    const int lds_hi = (srow + 64) * BK + sk;

    f32x4 acc[4][4];
    #pragma unroll
    for (int i = 0; i < 4; ++i)
        #pragma unroll
        for (int j = 0; j < 4; ++j)
            acc[i][j] = f32x4{0.f, 0.f, 0.f, 0.f};

    const int lr = lane & 15;
    const int kg = lane >> 4;
    const int b_rd_off = (wn * 64 + lr) * BK + kg * 8;

    // A fragment base pointers: 16B contiguous per lane (layout verified r11)
    const bf16_t* aF[4];
    #pragma unroll
    for (int i = 0; i < 4; ++i)
        aF[i] = Ab + (size_t)(row0 + wm * 64 + i * 16 + lr) * PD + kg * 8;

    // prologue: A(0) into regs, B(0) into buf 0
    bf16x8 afA[4], afB[4];
    #pragma unroll
    for (int i = 0; i < 4; ++i)
        afA[i] = *(const bf16x8*)(aF[i]);
    gload16(b0,           Bsb + lds_lo);
    gload16(b0 + 64 * PD, Bsb + lds_hi);
    __syncthreads();

    int cur = 0;
    for (int t = 0; t < NT; t += 2) {
        GSTEP(afA, afB, t);        // computes tile t,   prefetches t+1 -> afB
        GSTEP(afB, afA, t + 1);    // computes tile t+1, prefetches t+2 -> afA
    }

    // ---- Epilogue: LDS-transposed, vectorized; row metadata hoisted ----
    const int lrow_w  = wm * 16 + kg * 4;
    const int lcol_w  = wn * 64 + lr;
    const int rr = tid >> 3;                  // 0..31
    const int cg = tid & 7;                   // 0..7
    const int erow_local = (rr & 15) + (rr >> 4) * 64;

    int grow4[4], p04[4], p14[4];
    #pragma unroll
    for (int mi = 0; mi < 4; ++mi) {
        int crow = row0 + mi * 16 + erow_local;
        if constexpr (USE_MAP) {
            const int cc = crow < Mc ? crow : Mc - 1;   // clamped (store guarded)
            grow4[mi] = rowmap[cc];
        } else {
            grow4[mi] = crow;
        }
        int p0 = posids[2 * grow4[mi]];
        int p1 = posids[2 * grow4[mi] + 1];
        p04[mi] = p0 < 0 ? 0 : p0;
        p14[mi] = p1 < 0 ? 0 : p1;
    }

    #pragma unroll
    for (int mi = 0; mi < 4; ++mi) {
        __syncthreads();                      // staging/prev-slice reads done
        #pragma unroll
        for (int r = 0; r < 4; ++r)
            #pragma unroll
            for (int ni = 0; ni < 4; ++ni)
                Cs[(lrow_w + r) * LDSC + lcol_w + ni * 16] = acc[mi][ni][r];
        __syncthreads();                      // slice visible

        const int crow = row0 + mi * 16 + erow_local;
        if constexpr (USE_MAP) {
            if (crow >= Mc) continue;
            const float* t0 = ptab + (size_t)p04[mi] * HID + col0;
            const float* t1 = ptab + (size_t)PSZ * HID + (size_t)p14[mi] * HID + col0;
            float* orow = out + (size_t)grow4[mi] * HID + col0;
            #pragma unroll
            for (int j = 0; j < 4; ++j) {
                const int c = (cg + 8 * j) * 4;
                float4 v  = *(const float4*)&Cs[rr * LDSC + c];
                const float4 e0 = *(const float4*)(t0 + c);
                const float4 e1 = *(const float4*)(t1 + c);
                v.x += e0.x + e1.x;
                v.y += e0.y + e1.y;
                v.z += e0.z + e1.z;
                v.w += e0.w + e1.w;
                *(float4*)(orow + c) = v;
            }
        } else {
            const int grow = crow;
            float* orow = out + (size_t)grow * HID + col0;
            const int mk = mask[grow];
            if (mk) {
                const float4 z{0.f, 0.f, 0.f, 0.f};
                #pragma unroll
                for (int j = 0; j < 4; ++j)
                    *(float4*)(orow + (cg + 8 * j) * 4) = z;
            } else {
                const float* t0 = ptab + (size_t)p04[mi] * HID + col0;
                const float* t1 = ptab + (size_t)PSZ * HID + (size_t)p14[mi] * HID + col0;
                #pragma unroll
                for (int j = 0; j < 4; ++j) {
                    const int c = (cg + 8 * j) * 4;
                    float4 v  = *(const float4*)&Cs[rr * LDSC + c];
                    const float4 e0 = *(const float4*)(t0 + c);
                    const float4 e1 = *(const float4*)(t1 + c);
                    v.x += e0.x + e1.x;
                    v.y += e0.y + e1.y;
                    v.z += e0.z + e1.z;
                    v.w += e0.w + e1.w;
                    *(float4*)(orow + c) = v;
                }
            }
        }
    }
}

// ---------------- Fallback (fused kernel, used if ws too small) -------------
constexpr int LDSS = 40;

__global__ __launch_bounds__(256, 2)
void vpe_kernel(const float* __restrict__ pv,
                const int* __restrict__ posids,
                const int* __restrict__ mask,
                const float* __restrict__ W,
                const float* __restrict__ ptab,
                float* __restrict__ out)
{
    __shared__ alignas(16) bf16_t As[2][BM * LDSS];
    __shared__ alignas(16) bf16_t Bs[2][BM * LDSS];

    const int nwg = gridDim.x;
    const int cpx = nwg >> 3;
    const int logical = (blockIdx.x & 7) * cpx + (blockIdx.x >> 3);
    const int mt = logical / 6;
    const int nt = logical - mt * 6;
    const int row0 = mt * BM;
    const int col0 = nt * BN;

    const int tid  = threadIdx.x;
    const int lane = tid & 63;
    const int wid  = tid >> 6;
    const int wm   = wid >> 1;
    const int wn   = wid & 1;
    const int srow = tid >> 1;
    const int scol = (tid & 1) << 4;

    const float* aptr = pv + (size_t)(row0 + srow) * PD + scol;
    const float* bptr = W  + (size_t)(col0 + srow) * PD + scol;
    const int lds_w_off = srow * LDSS + scol;

    f32x4 acc[4][4];
    #pragma unroll
    for (int i = 0; i < 4; ++i)
        #pragma unroll
        for (int j = 0; j < 4; ++j)
            acc[i][j] = f32x4{0.f, 0.f, 0.f, 0.f};

    const int lr = lane & 15;
    const int kg = lane >> 4;
    const int a_rd_off = (wm * 64 + lr) * LDSS + kg * 8;
    const int b_rd_off = (wn * 64 + lr) * LDSS + kg * 8;

    float4 ra[4], rb[4];
    #pragma unroll
    for (int q = 0; q < 4; ++q) {
        ra[q] = *(const float4*)(aptr + q * 4);
        rb[q] = *(const float4*)(bptr + q * 4);
    }
    {
        bf16x8 av0 = cvt8_affine(ra[0], ra[1], 2.f, -1.f);
        bf16x8 av1 = cvt8_affine(ra[2], ra[3], 2.f, -1.f);
        bf16x8 bv0 = cvt8_affine(rb[0], rb[1], 1.f, 0.f);
        bf16x8 bv1 = cvt8_affine(rb[2], rb[3], 1.f, 0.f);
        *(bf16x8*)(&As[0][lds_w_off])     = av0;
        *(bf16x8*)(&As[0][lds_w_off] + 8) = av1;
        *(bf16x8*)(&Bs[0][lds_w_off])     = bv0;
        *(bf16x8*)(&Bs[0][lds_w_off] + 8) = bv1;
    }
    __syncthreads();

    int cur = 0;
    for (int t = 0; t < NT - 1; ++t) {
        const int k1 = (t + 1) * BK;
        #pragma unroll
        for (int q = 0; q < 4; ++q) {
            ra[q] = *(const float4*)(aptr + k1 + q * 4);
            rb[q] = *(const float4*)(bptr + k1 + q * 4);
        }
        bf16x8 af[4], bfv[4];
        #pragma unroll
        for (int i = 0; i < 4; ++i) {
            af[i]  = *(const bf16x8*)(&As[cur][a_rd_off] + i * 16 * LDSS);
            bfv[i] = *(const bf16x8*)(&Bs[cur][b_rd_off] + i * 16 * LDSS);
        }
        #pragma unroll
        for (int i = 0; i < 4; ++i)
            #pragma unroll
            for (int j = 0; j < 4; ++j)
                acc[i][j] = __builtin_amdgcn_mfma_f32_16x16x32_bf16(
                    af[i], bfv[j], acc[i][j], 0, 0, 0);
        {
            bf16x8 av0 = cvt8_affine(ra[0], ra[1], 2.f, -1.f);
            bf16x8 av1 = cvt8_affine(ra[2], ra[3], 2.f, -1.f);
            bf16x8 bv0 = cvt8_affine(rb[0], rb[1], 1.f, 0.f);
            bf16x8 bv1 = cvt8_affine(rb[2], rb[3], 1.f, 0.f);
            const int nb = cur ^ 1;
            *(bf16x8*)(&As[nb][lds_w_off])     = av0;
            *(bf16x8*)(&As[nb][lds_w_off] + 8) = av1;
            *(bf16x8*)(&Bs[nb][lds_w_off])     = bv0;
            *(bf16x8*)(&Bs[nb][lds_w_off] + 8) = bv1;
        }
        __syncthreads();
        cur ^= 1;
    }
    {
        bf16x8 af[4], bfv[4];
        #pragma unroll
        for (int i = 0; i < 4; ++i) {
            af[i]  = *(const bf16x8*)(&As[cur][a_rd_off] + i * 16 * LDSS);
            bfv[i] = *(const bf16x8*)(&Bs[cur][b_rd_off] + i * 16 * LDSS);
        }
        #pragma unroll
        for (int i = 0; i < 4; ++i)
            #pragma unroll
            for (int j = 0; j < 4; ++j)
                acc[i][j] = __builtin_amdgcn_mfma_f32_16x16x32_bf16(
                    af[i], bfv[j], acc[i][j], 0, 0, 0);
    }
    #pragma unroll
    for (int mi = 0; mi < 4; ++mi) {
        #pragma unroll
        for (int r = 0; r < 4; ++r) {
            const int grow = row0 + wm * 64 + mi * 16 + kg * 4 + r;
            const int mk = mask[grow];
            int p0 = posids[2 * grow];
            int p1 = posids[2 * grow + 1];
            p0 = p0 < 0 ? 0 : p0;
            p1 = p1 < 0 ? 0 : p1;
            const float* t0 = ptab + (size_t)p0 * HID;
            const float* t1 = ptab + (size_t)PSZ * HID + (size_t)p1 * HID;
            float* orow = out + (size_t)grow * HID;
            #pragma unroll
            for (int ni = 0; ni < 4; ++ni) {
                const int col = col0 + wn * 64 + ni * 16 + lr;
                const float v = acc[mi][ni][r] + t0[col] + t1[col];
                orow[col] = mk ? 0.f : v;
            }
        }
    }
}

extern "C" void kernel_launch(void* const* d_in, const int* in_sizes, int n_in,
                              void* d_out, int out_size, void* d_ws, size_t ws_size,
                              hipStream_t stream) {
    (void)in_sizes; (void)n_in; (void)out_size;
    const float* pv     = (const float*)d_in[0];
    const int*   posids = (const int*)d_in[1];
    const int*   mask   = (const int*)d_in[2];
    const float* W      = (const float*)d_in[3];
    const float* ptab   = (const float*)d_in[4];
    float*       out    = (float*)d_out;

    const size_t AB_B = PVN * sizeof(bf16_t);   // 96 MB
    const size_t WB_B = WN * sizeof(bf16_t);    // 1.125 MB
    const size_t RM_B = (size_t)MT * 4;         // 256 KB
    const size_t need1 = AB_B + WB_B;
    const size_t need2 = AB_B + WB_B + RM_B + 16;
    const int grid = (MT / BM) * (HID / BN);    // 3072

    if (ws_size >= need2) {
        bf16_t* Ab   = (bf16_t*)d_ws;
        bf16_t* Wb   = Ab + PVN;
        int* rowmap  = (int*)((char*)d_ws + AB_B + WB_B);
        int* counter = (int*)((char*)d_ws + AB_B + WB_B + RM_B);
        hipMemsetAsync(counter, 0, 16, stream);
        hipLaunchKernelGGL(compact_cvt, dim3(1088), dim3(256), 0, stream,
                           pv, mask, W, Ab, Wb, rowmap, counter, out);
        hipLaunchKernelGGL((gemm_kernel<true>), dim3(grid), dim3(256), 0, stream,
                           Ab, Wb, posids, mask, ptab, out, rowmap, counter);
    } else if (ws_size >= need1) {
        bf16_t* Ab = (bf16_t*)d_ws;
        bf16_t* Wb = Ab + PVN;
        hipLaunchKernelGGL(cvt_kernel, dim3(2048), dim3(256), 0, stream,
                           pv, W, Ab, Wb);
        hipLaunchKernelGGL((gemm_kernel<false>), dim3(grid), dim3(256), 0, stream,
                           Ab, Wb, posids, mask, ptab, out, nullptr, nullptr);
    } else {
        hipLaunchKernelGGL(vpe_kernel, dim3(grid), dim3(256), 0, stream,
                           pv, posids, mask, W, ptab, out);
    }
}

// Round 16
// 179.369 us; speedup vs baseline: 1.1631x; 1.1469x over previous
//
#include <hip/hip_runtime.h>
#include <hip/hip_bf16.h>

typedef __bf16 bf16_t;
typedef bf16_t bf16x4 __attribute__((ext_vector_type(4)));
typedef bf16_t bf16x8 __attribute__((ext_vector_type(8)));
typedef float f32x4 __attribute__((ext_vector_type(4)));

constexpr int NB   = 16;
constexpr int NN   = 4096;
constexpr int PD   = 768;    // patch dim (K)
constexpr int HID  = 768;    // hidden (N out)
constexpr int PSZ  = 10240;  // pos table size
constexpr int MT   = NB * NN;        // 65536 rows
constexpr int BM   = 128;
constexpr int BN   = 128;
constexpr int BK   = 32;
constexpr int NT   = PD / BK;        // 24 k-tiles
constexpr int LDSC = 132;            // padded C-slice row stride (floats)
constexpr size_t PVN = (size_t)MT * PD;    // 50331648
constexpr size_t WN  = (size_t)HID * PD;   // 589824

__device__ __forceinline__ bf16x8 cvt8_affine(const float4& x, const float4& y,
                                              float s, float o) {
    bf16x8 r;
    r[0] = (bf16_t)__builtin_fmaf(s, x.x, o);
    r[1] = (bf16_t)__builtin_fmaf(s, x.y, o);
    r[2] = (bf16_t)__builtin_fmaf(s, x.z, o);
    r[3] = (bf16_t)__builtin_fmaf(s, x.w, o);
    r[4] = (bf16_t)__builtin_fmaf(s, y.x, o);
    r[5] = (bf16_t)__builtin_fmaf(s, y.y, o);
    r[6] = (bf16_t)__builtin_fmaf(s, y.z, o);
    r[7] = (bf16_t)__builtin_fmaf(s, y.w, o);
    return r;
}

__device__ __forceinline__ bf16x4 cvt4_affine(const float4& x, float s, float o) {
    bf16x4 r;
    r[0] = (bf16_t)__builtin_fmaf(s, x.x, o);
    r[1] = (bf16_t)__builtin_fmaf(s, x.y, o);
    r[2] = (bf16_t)__builtin_fmaf(s, x.z, o);
    r[3] = (bf16_t)__builtin_fmaf(s, x.w, o);
    return r;
}

// ------- Pass 1a: mask-ballot compaction + cvt + inline zero-fill -----------
// 2048 blocks x 32 rows (finer tail balance) + 64 blocks for W conversion.
__global__ __launch_bounds__(256)
void compact_cvt(const float* __restrict__ pv,
                 const int* __restrict__ mask,
                 const float* __restrict__ W,
                 bf16_t* __restrict__ Ab,
                 bf16_t* __restrict__ Wb,
                 int* __restrict__ rowmap,
                 int* __restrict__ counter,
                 float* __restrict__ out)
{
    const int bid = blockIdx.x;
    const int tid = threadIdx.x;
    if (bid < 2048) {
        __shared__ int ls_slot[32];
        const int rowbase = bid * 32;
        const int lane = tid & 63;
        const int wv   = tid >> 6;
        if (wv == 0) {
            const bool valid = lane < 32;
            const int mk = valid ? mask[rowbase + lane] : 1;   // !=0 -> masked
            const unsigned long long b = __ballot(mk == 0);    // bits only <32
            const int total = __popcll(b);
            const int pos = __popcll(b & ((1ull << lane) - 1ull));
            int gb = 0;
            if (lane == 0) gb = atomicAdd(counter, total);
            gb = __shfl(gb, 0);
            if (valid) {
                const int slot = (mk == 0) ? (gb + pos) : -1;
                ls_slot[lane] = slot;
                if (slot >= 0) rowmap[slot] = rowbase + lane;
            }
        }
        __syncthreads();
        for (int i = wv; i < 32; i += 4) {
            const int slot = ls_slot[i];
            const int grow = rowbase + i;
            if (slot >= 0) {
                const float* src = pv + (size_t)grow * PD + lane * 12;
                bf16_t* dst = Ab + (size_t)slot * PD + lane * 12;
                #pragma unroll
                for (int q = 0; q < 3; ++q) {
                    const float4 v = *(const float4*)(src + q * 4);
                    *(bf16x4*)(dst + q * 4) = cvt4_affine(v, 2.f, -1.f);
                }
            } else {
                float* dst = out + (size_t)grow * HID + lane * 12;
                const float4 z{0.f, 0.f, 0.f, 0.f};
                #pragma unroll
                for (int q = 0; q < 3; ++q)
                    *(float4*)(dst + q * 4) = z;
            }
        }
    } else {
        const size_t nu = WN / 8;
        for (size_t u = (size_t)(bid - 2048) * 256 + tid; u < nu;
             u += (size_t)64 * 256) {
            const float4 x = ((const float4*)W)[2 * u];
            const float4 y = ((const float4*)W)[2 * u + 1];
            *(bf16x8*)(Wb + 8 * u) = cvt8_affine(x, y, 1.f, 0.f);
        }
    }
}

// ------- Pass 1b (non-compacting fallback): plain fp32->bf16 convert --------
__global__ __launch_bounds__(256)
void cvt_kernel(const float* __restrict__ pv, const float* __restrict__ W,
                bf16_t* __restrict__ Ab, bf16_t* __restrict__ Wb)
{
    const size_t nunits = (PVN + WN) / 8;
    const size_t stride = (size_t)gridDim.x * blockDim.x;
    for (size_t u = (size_t)blockIdx.x * blockDim.x + threadIdx.x;
         u < nunits; u += stride) {
        if (u < PVN / 8) {
            const float4 x = ((const float4*)pv)[2 * u];
            const float4 y = ((const float4*)pv)[2 * u + 1];
            *(bf16x8*)(Ab + 8 * u) = cvt8_affine(x, y, 2.f, -1.f);
        } else {
            const size_t v = u - PVN / 8;
            const float4 x = ((const float4*)W)[2 * v];
            const float4 y = ((const float4*)W)[2 * v + 1];
            *(bf16x8*)(Wb + 8 * v) = cvt8_affine(x, y, 1.f, 0.f);
        }
    }
}

// ---------------- Pass 2: bf16 MFMA GEMM with global_load_lds ---------------
__device__ __forceinline__ void gload16(const void* g, void* l) {
    __builtin_amdgcn_global_load_lds(
        (const __attribute__((address_space(1))) void*)g,
        (__attribute__((address_space(3))) void*)l, 16, 0, 0);
}

template <bool USE_MAP>
__global__ __launch_bounds__(256, 4)
void gemm_kernel(const bf16_t* __restrict__ Ab,
                 const bf16_t* __restrict__ Wb,
                 const int* __restrict__ posids,
                 const int* __restrict__ mask,
                 const float* __restrict__ ptab,
                 float* __restrict__ out,
                 const int* __restrict__ rowmap,
                 const int* __restrict__ counter)
{
    __shared__ alignas(16) unsigned char smem[2 * (BM * BK + BN * BK) * 2];
    bf16_t* const Asb = (bf16_t*)smem;                 // [2][BM*BK]
    bf16_t* const Bsb = (bf16_t*)smem + 2 * BM * BK;   // [2][BN*BK]
    float*  const Cs  = (float*)smem;                  // [32][LDSC]

    int Mc = MT;
    int mt, nt;
    const int bid = blockIdx.x;
    if constexpr (USE_MAP) {
        Mc = counter[0];
        const int Mtiles = (Mc + BM - 1) / BM;
        const int nact = Mtiles * 6;
        if (bid >= nact) return;      // exits round-robin across XCDs
        // Dynamic bijective XCD swizzle over the ACTIVE block count.
        const int q = nact >> 3, rm = nact & 7;
        const int x = bid & 7, i = bid >> 3;
        const int logical = (x < rm ? x * (q + 1) : rm * (q + 1) + (x - rm) * q) + i;
        mt = logical / 6;
        nt = logical - mt * 6;
    } else {
        const int nwg = gridDim.x;
        const int cpx = nwg >> 3;
        const int logical = (bid & 7) * cpx + (bid >> 3);
        mt = logical / 6;
        nt = logical - mt * 6;
    }
    const int row0 = mt * BM;
    const int col0 = nt * BN;

    const int tid  = threadIdx.x;
    const int lane = tid & 63;
    const int wid  = tid >> 6;
    const int wm   = wid >> 1;
    const int wn   = wid & 1;

    const int srow = tid >> 2;          // 0..63
    const int sk   = (tid & 3) * 8;     // 0,8,16,24
    const bf16_t* a0 = Ab + (size_t)(row0 + srow) * PD + sk;
    const bf16_t* b0 = Wb + (size_t)(col0 + srow) * PD + sk;
    const int lds_lo = srow * BK + sk;
    const int lds_hi = (srow + 64) * BK + sk;

    f32x4 acc[4][4];
    #pragma unroll
    for (int i = 0; i < 4; ++i)
        #pragma unroll
        for (int j = 0; j < 4; ++j)
            acc[i][j] = f32x4{0.f, 0.f, 0.f, 0.f};

    const int lr = lane & 15;
    const int kg = lane >> 4;
    const int a_rd_off = (wm * 64 + lr) * BK + kg * 8;
    const int b_rd_off = (wn * 64 + lr) * BK + kg * 8;

    // prologue: stage tile 0 into buf 0
    gload16(a0,           Asb + lds_lo);
    gload16(a0 + 64 * PD, Asb + lds_hi);
    gload16(b0,           Bsb + lds_lo);
    gload16(b0 + 64 * PD, Bsb + lds_hi);
    __syncthreads();

    int cur = 0;
    for (int t = 0; t < NT; ++t) {
        if (t + 1 < NT) {
            const int k1 = (t + 1) * BK;
            const int nb = cur ^ 1;
            gload16(a0 + k1,           Asb + nb * (BM * BK) + lds_lo);
            gload16(a0 + 64 * PD + k1, Asb + nb * (BM * BK) + lds_hi);
            gload16(b0 + k1,           Bsb + nb * (BN * BK) + lds_lo);
            gload16(b0 + 64 * PD + k1, Bsb + nb * (BN * BK) + lds_hi);
        }

        bf16x8 af[4], bfv[4];
        #pragma unroll
        for (int i = 0; i < 4; ++i) {
            af[i]  = *(const bf16x8*)(Asb + cur * (BM * BK) + a_rd_off + i * 16 * BK);
            bfv[i] = *(const bf16x8*)(Bsb + cur * (BN * BK) + b_rd_off + i * 16 * BK);
        }
        #pragma unroll
        for (int i = 0; i < 4; ++i)
            #pragma unroll
            for (int j = 0; j < 4; ++j)
                acc[i][j] = __builtin_amdgcn_mfma_f32_16x16x32_bf16(
                    af[i], bfv[j], acc[i][j], 0, 0, 0);

        __syncthreads();
        cur ^= 1;
    }

    // ---- Epilogue: LDS-transposed, vectorized; row metadata hoisted ----
    const int lrow_w  = wm * 16 + kg * 4;
    const int lcol_w  = wn * 64 + lr;
    const int rr = tid >> 3;                  // 0..31
    const int cg = tid & 7;                   // 0..7
    const int erow_local = (rr & 15) + (rr >> 4) * 64;

    int grow4[4], p04[4], p14[4];
    #pragma unroll
    for (int mi = 0; mi < 4; ++mi) {
        int crow = row0 + mi * 16 + erow_local;
        if constexpr (USE_MAP) {
            const int cc = crow < Mc ? crow : Mc - 1;   // clamped (store guarded)
            grow4[mi] = rowmap[cc];
        } else {
            grow4[mi] = crow;
        }
        int p0 = posids[2 * grow4[mi]];
        int p1 = posids[2 * grow4[mi] + 1];
        p04[mi] = p0 < 0 ? 0 : p0;
        p14[mi] = p1 < 0 ? 0 : p1;
    }

    #pragma unroll
    for (int mi = 0; mi < 4; ++mi) {
        if (mi) __syncthreads();
        #pragma unroll
        for (int r = 0; r < 4; ++r)
            #pragma unroll
            for (int ni = 0; ni < 4; ++ni)
                Cs[(lrow_w + r) * LDSC + lcol_w + ni * 16] = acc[mi][ni][r];
        __syncthreads();

        const int crow = row0 + mi * 16 + erow_local;
        if constexpr (USE_MAP) {
            if (crow >= Mc) continue;
            const float* t0 = ptab + (size_t)p04[mi] * HID + col0;
            const float* t1 = ptab + (size_t)PSZ * HID + (size_t)p14[mi] * HID + col0;
            float* orow = out + (size_t)grow4[mi] * HID + col0;
            #pragma unroll
            for (int j = 0; j < 4; ++j) {
                const int c = (cg + 8 * j) * 4;
                float4 v  = *(const float4*)&Cs[rr * LDSC + c];
                const float4 e0 = *(const float4*)(t0 + c);
                const float4 e1 = *(const float4*)(t1 + c);
                v.x += e0.x + e1.x;
                v.y += e0.y + e1.y;
                v.z += e0.z + e1.z;
                v.w += e0.w + e1.w;
                *(float4*)(orow + c) = v;
            }
        } else {
            const int grow = crow;
            float* orow = out + (size_t)grow * HID + col0;
            const int mk = mask[grow];
            if (mk) {
                const float4 z{0.f, 0.f, 0.f, 0.f};
                #pragma unroll
                for (int j = 0; j < 4; ++j)
                    *(float4*)(orow + (cg + 8 * j) * 4) = z;
            } else {
                const float* t0 = ptab + (size_t)p04[mi] * HID + col0;
                const float* t1 = ptab + (size_t)PSZ * HID + (size_t)p14[mi] * HID + col0;
                #pragma unroll
                for (int j = 0; j < 4; ++j) {
                    const int c = (cg + 8 * j) * 4;
                    float4 v  = *(const float4*)&Cs[rr * LDSC + c];
                    const float4 e0 = *(const float4*)(t0 + c);
                    const float4 e1 = *(const float4*)(t1 + c);
                    v.x += e0.x + e1.x;
                    v.y += e0.y + e1.y;
                    v.z += e0.z + e1.z;
                    v.w += e0.w + e1.w;
                    *(float4*)(orow + c) = v;
                }
            }
        }
    }
}

// ---------------- Fallback (fused kernel, used if ws too small) -------------
constexpr int LDSS = 40;

__global__ __launch_bounds__(256, 2)
void vpe_kernel(const float* __restrict__ pv,
                const int* __restrict__ posids,
                const int* __restrict__ mask,
                const float* __restrict__ W,
                const float* __restrict__ ptab,
                float* __restrict__ out)
{
    __shared__ alignas(16) bf16_t As[2][BM * LDSS];
    __shared__ alignas(16) bf16_t Bs[2][BM * LDSS];

    const int nwg = gridDim.x;
    const int cpx = nwg >> 3;
    const int logical = (blockIdx.x & 7) * cpx + (blockIdx.x >> 3);
    const int mt = logical / 6;
    const int nt = logical - mt * 6;
    const int row0 = mt * BM;
    const int col0 = nt * BN;

    const int tid  = threadIdx.x;
    const int lane = tid & 63;
    const int wid  = tid >> 6;
    const int wm   = wid >> 1;
    const int wn   = wid & 1;
    const int srow = tid >> 1;
    const int scol = (tid & 1) << 4;

    const float* aptr = pv + (size_t)(row0 + srow) * PD + scol;
    const float* bptr = W  + (size_t)(col0 + srow) * PD + scol;
    const int lds_w_off = srow * LDSS + scol;

    f32x4 acc[4][4];
    #pragma unroll
    for (int i = 0; i < 4; ++i)
        #pragma unroll
        for (int j = 0; j < 4; ++j)
            acc[i][j] = f32x4{0.f, 0.f, 0.f, 0.f};

    const int lr = lane & 15;
    const int kg = lane >> 4;
    const int a_rd_off = (wm * 64 + lr) * LDSS + kg * 8;
    const int b_rd_off = (wn * 64 + lr) * LDSS + kg * 8;

    float4 ra[4], rb[4];
    #pragma unroll
    for (int q = 0; q < 4; ++q) {
        ra[q] = *(const float4*)(aptr + q * 4);
        rb[q] = *(const float4*)(bptr + q * 4);
    }
    {
        bf16x8 av0 = cvt8_affine(ra[0], ra[1], 2.f, -1.f);
        bf16x8 av1 = cvt8_affine(ra[2], ra[3], 2.f, -1.f);
        bf16x8 bv0 = cvt8_affine(rb[0], rb[1], 1.f, 0.f);
        bf16x8 bv1 = cvt8_affine(rb[2], rb[3], 1.f, 0.f);
        *(bf16x8*)(&As[0][lds_w_off])     = av0;
        *(bf16x8*)(&As[0][lds_w_off] + 8) = av1;
        *(bf16x8*)(&Bs[0][lds_w_off])     = bv0;
        *(bf16x8*)(&Bs[0][lds_w_off] + 8) = bv1;
    }
    __syncthreads();

    int cur = 0;
    for (int t = 0; t < NT - 1; ++t) {
        const int k1 = (t + 1) * BK;
        #pragma unroll
        for (int q = 0; q < 4; ++q) {
            ra[q] = *(const float4*)(aptr + k1 + q * 4);
            rb[q] = *(const float4*)(bptr + k1 + q * 4);
        }
        bf16x8 af[4], bfv[4];
        #pragma unroll
        for (int i = 0; i < 4; ++i) {
            af[i]  = *(const bf16x8*)(&As[cur][a_rd_off] + i * 16 * LDSS);
            bfv[i] = *(const bf16x8*)(&Bs[cur][b_rd_off] + i * 16 * LDSS);
        }
        #pragma unroll
        for (int i = 0; i < 4; ++i)
            #pragma unroll
            for (int j = 0; j < 4; ++j)
                acc[i][j] = __builtin_amdgcn_mfma_f32_16x16x32_bf16(
                    af[i], bfv[j], acc[i][j], 0, 0, 0);
        {
            bf16x8 av0 = cvt8_affine(ra[0], ra[1], 2.f, -1.f);
            bf16x8 av1 = cvt8_affine(ra[2], ra[3], 2.f, -1.f);
            bf16x8 bv0 = cvt8_affine(rb[0], rb[1], 1.f, 0.f);
            bf16x8 bv1 = cvt8_affine(rb[2], rb[3], 1.f, 0.f);
            const int nb = cur ^ 1;
            *(bf16x8*)(&As[nb][lds_w_off])     = av0;
            *(bf16x8*)(&As[nb][lds_w_off] + 8) = av1;
            *(bf16x8*)(&Bs[nb][lds_w_off])     = bv0;
            *(bf16x8*)(&Bs[nb][lds_w_off] + 8) = bv1;
        }
        __syncthreads();
        cur ^= 1;
    }
    {
        bf16x8 af[4], bfv[4];
        #pragma unroll
        for (int i = 0; i < 4; ++i) {
            af[i]  = *(const bf16x8*)(&As[cur][a_rd_off] + i * 16 * LDSS);
            bfv[i] = *(const bf16x8*)(&Bs[cur][b_rd_off] + i * 16 * LDSS);
        }
        #pragma unroll
        for (int i = 0; i < 4; ++i)
            #pragma unroll
            for (int j = 0; j < 4; ++j)
                acc[i][j] = __builtin_amdgcn_mfma_f32_16x16x32_bf16(
                    af[i], bfv[j], acc[i][j], 0, 0, 0);
    }
    #pragma unroll
    for (int mi = 0; mi < 4; ++mi) {
        #pragma unroll
        for (int r = 0; r < 4; ++r) {
            const int grow = row0 + wm * 64 + mi * 16 + kg * 4 + r;
            const int mk = mask[grow];
            int p0 = posids[2 * grow];
            int p1 = posids[2 * grow + 1];
            p0 = p0 < 0 ? 0 : p0;
            p1 = p1 < 0 ? 0 : p1;
            const float* t0 = ptab + (size_t)p0 * HID;
            const float* t1 = ptab + (size_t)PSZ * HID + (size_t)p1 * HID;
            float* orow = out + (size_t)grow * HID;
            #pragma unroll
            for (int ni = 0; ni < 4; ++ni) {
                const int col = col0 + wn * 64 + ni * 16 + lr;
                const float v = acc[mi][ni][r] + t0[col] + t1[col];
                orow[col] = mk ? 0.f : v;
            }
        }
    }
}

extern "C" void kernel_launch(void* const* d_in, const int* in_sizes, int n_in,
                              void* d_out, int out_size, void* d_ws, size_t ws_size,
                              hipStream_t stream) {
    (void)in_sizes; (void)n_in; (void)out_size;
    const float* pv     = (const float*)d_in[0];
    const int*   posids = (const int*)d_in[1];
    const int*   mask   = (const int*)d_in[2];
    const float* W      = (const float*)d_in[3];
    const float* ptab   = (const float*)d_in[4];
    float*       out    = (float*)d_out;

    const size_t AB_B = PVN * sizeof(bf16_t);   // 96 MB
    const size_t WB_B = WN * sizeof(bf16_t);    // 1.125 MB
    const size_t RM_B = (size_t)MT * 4;         // 256 KB
    const size_t need1 = AB_B + WB_B;
    const size_t need2 = AB_B + WB_B + RM_B + 16;
    const int grid = (MT / BM) * (HID / BN);    // 3072

    if (ws_size >= need2) {
        bf16_t* Ab   = (bf16_t*)d_ws;
        bf16_t* Wb   = Ab + PVN;
        int* rowmap  = (int*)((char*)d_ws + AB_B + WB_B);
        int* counter = (int*)((char*)d_ws + AB_B + WB_B + RM_B);
        hipMemsetAsync(counter, 0, 16, stream);
        hipLaunchKernelGGL(compact_cvt, dim3(2112), dim3(256), 0, stream,
                           pv, mask, W, Ab, Wb, rowmap, counter, out);
        hipLaunchKernelGGL((gemm_kernel<true>), dim3(grid), dim3(256), 0, stream,
                           Ab, Wb, posids, mask, ptab, out, rowmap, counter);
    } else if (ws_size >= need1) {
        bf16_t* Ab = (bf16_t*)d_ws;
        bf16_t* Wb = Ab + PVN;
        hipLaunchKernelGGL(cvt_kernel, dim3(2048), dim3(256), 0, stream,
                           pv, W, Ab, Wb);
        hipLaunchKernelGGL((gemm_kernel<false>), dim3(grid), dim3(256), 0, stream,
                           Ab, Wb, posids, mask, ptab, out, nullptr, nullptr);
    } else {
        hipLaunchKernelGGL(vpe_kernel, dim3(grid), dim3(256), 0, stream,
                           pv, posids, mask, W, ptab, out);
    }
}

// Round 17
// 167.528 us; speedup vs baseline: 1.2453x; 1.0707x over previous
//
#include <hip/hip_runtime.h>
#include <hip/hip_bf16.h>

typedef __bf16 bf16_t;
typedef bf16_t bf16x4 __attribute__((ext_vector_type(4)));
typedef bf16_t bf16x8 __attribute__((ext_vector_type(8)));
typedef float f32x4 __attribute__((ext_vector_type(4)));

constexpr int NB   = 16;
constexpr int NN   = 4096;
constexpr int PD   = 768;    // patch dim (K)
constexpr int HID  = 768;    // hidden (N out)
constexpr int PSZ  = 10240;  // pos table size
constexpr int MT   = NB * NN;        // 65536 rows
constexpr int BM   = 128;
constexpr int BN   = 128;
constexpr int BK   = 32;
constexpr int NT   = PD / BK;        // 24 k-tiles
constexpr int LDSC = 132;            // padded C-slice row stride (floats)
constexpr size_t PVN = (size_t)MT * PD;    // 50331648
constexpr size_t WN  = (size_t)HID * PD;   // 589824

__device__ __forceinline__ bf16x8 cvt8_affine(const float4& x, const float4& y,
                                              float s, float o) {
    bf16x8 r;
    r[0] = (bf16_t)__builtin_fmaf(s, x.x, o);
    r[1] = (bf16_t)__builtin_fmaf(s, x.y, o);
    r[2] = (bf16_t)__builtin_fmaf(s, x.z, o);
    r[3] = (bf16_t)__builtin_fmaf(s, x.w, o);
    r[4] = (bf16_t)__builtin_fmaf(s, y.x, o);
    r[5] = (bf16_t)__builtin_fmaf(s, y.y, o);
    r[6] = (bf16_t)__builtin_fmaf(s, y.z, o);
    r[7] = (bf16_t)__builtin_fmaf(s, y.w, o);
    return r;
}

__device__ __forceinline__ bf16x4 cvt4_affine(const float4& x, float s, float o) {
    bf16x4 r;
    r[0] = (bf16_t)__builtin_fmaf(s, x.x, o);
    r[1] = (bf16_t)__builtin_fmaf(s, x.y, o);
    r[2] = (bf16_t)__builtin_fmaf(s, x.z, o);
    r[3] = (bf16_t)__builtin_fmaf(s, x.w, o);
    return r;
}

// ------- Pass 1a: mask-ballot compaction + cvt + inline zero-fill -----------
__global__ __launch_bounds__(256)
void compact_cvt(const float* __restrict__ pv,
                 const int* __restrict__ mask,
                 const float* __restrict__ W,
                 bf16_t* __restrict__ Ab,
                 bf16_t* __restrict__ Wb,
                 int* __restrict__ rowmap,
                 int* __restrict__ counter,
                 float* __restrict__ out)
{
    const int bid = blockIdx.x;
    const int tid = threadIdx.x;
    if (bid < 1024) {
        __shared__ int ls_slot[64];
        const int rowbase = bid * 64;
        const int lane = tid & 63;
        const int wv   = tid >> 6;
        if (wv == 0) {
            const int mk = mask[rowbase + lane];          // !=0 -> masked
            const unsigned long long b = __ballot(mk == 0);
            const int total = __popcll(b);
            const int pos = __popcll(b & ((1ull << lane) - 1ull));
            int gb = 0;
            if (lane == 0) gb = atomicAdd(counter, total);
            gb = __shfl(gb, 0);
            const int slot = (mk == 0) ? (gb + pos) : -1;
            ls_slot[lane] = slot;
            if (slot >= 0) rowmap[slot] = rowbase + lane;
        }
        __syncthreads();
        for (int i = wv; i < 64; i += 4) {
            const int slot = ls_slot[i];
            const int grow = rowbase + i;
            if (slot >= 0) {
                const float* src = pv + (size_t)grow * PD + lane * 12;
                bf16_t* dst = Ab + (size_t)slot * PD + lane * 12;
                #pragma unroll
                for (int q = 0; q < 3; ++q) {
                    const float4 v = *(const float4*)(src + q * 4);
                    *(bf16x4*)(dst + q * 4) = cvt4_affine(v, 2.f, -1.f);
                }
            } else {
                float* dst = out + (size_t)grow * HID + lane * 12;
                const float4 z{0.f, 0.f, 0.f, 0.f};
                #pragma unroll
                for (int q = 0; q < 3; ++q)
                    *(float4*)(dst + q * 4) = z;
            }
        }
    } else {
        const size_t nu = WN / 8;
        for (size_t u = (size_t)(bid - 1024) * 256 + tid; u < nu;
             u += (size_t)64 * 256) {
            const float4 x = ((const float4*)W)[2 * u];
            const float4 y = ((const float4*)W)[2 * u + 1];
            *(bf16x8*)(Wb + 8 * u) = cvt8_affine(x, y, 1.f, 0.f);
        }
    }
}

// ------- Pass 1b (non-compacting fallback): plain fp32->bf16 convert --------
__global__ __launch_bounds__(256)
void cvt_kernel(const float* __restrict__ pv, const float* __restrict__ W,
                bf16_t* __restrict__ Ab, bf16_t* __restrict__ Wb)
{
    const size_t nunits = (PVN + WN) / 8;
    const size_t stride = (size_t)gridDim.x * blockDim.x;
    for (size_t u = (size_t)blockIdx.x * blockDim.x + threadIdx.x;
         u < nunits; u += stride) {
        if (u < PVN / 8) {
            const float4 x = ((const float4*)pv)[2 * u];
            const float4 y = ((const float4*)pv)[2 * u + 1];
            *(bf16x8*)(Ab + 8 * u) = cvt8_affine(x, y, 2.f, -1.f);
        } else {
            const size_t v = u - PVN / 8;
            const float4 x = ((const float4*)W)[2 * v];
            const float4 y = ((const float4*)W)[2 * v + 1];
            *(bf16x8*)(Wb + 8 * v) = cvt8_affine(x, y, 1.f, 0.f);
        }
    }
}

// ---------------- Pass 2: bf16 MFMA GEMM with global_load_lds ---------------
__device__ __forceinline__ void gload16(const void* g, void* l) {
    __builtin_amdgcn_global_load_lds(
        (const __attribute__((address_space(1))) void*)g,
        (__attribute__((address_space(3))) void*)l, 16, 0, 0);
}

template <bool USE_MAP>
__global__ __launch_bounds__(256, 2)
void gemm_kernel(const bf16_t* __restrict__ Ab,
                 const bf16_t* __restrict__ Wb,
                 const int* __restrict__ posids,
                 const int* __restrict__ mask,
                 const float* __restrict__ ptab,
                 float* __restrict__ out,
                 const int* __restrict__ rowmap,
                 const int* __restrict__ counter)
{
    __shared__ alignas(16) unsigned char smem[2 * (BM * BK + BN * BK) * 2];
    bf16_t* const Asb = (bf16_t*)smem;                 // [2][BM*BK]
    bf16_t* const Bsb = (bf16_t*)smem + 2 * BM * BK;   // [2][BN*BK]
    float*  const Cs  = (float*)smem;                  // [32][LDSC]

    int Mc = MT;
    int mt, nt;
    const int bid = blockIdx.x;
    if constexpr (USE_MAP) {
        Mc = counter[0];
        const int Mtiles = (Mc + BM - 1) / BM;
        const int nact = Mtiles * 6;
        if (bid >= nact) return;      // exits round-robin across XCDs
        // Dynamic bijective XCD swizzle over the ACTIVE block count.
        const int q = nact >> 3, rm = nact & 7;
        const int x = bid & 7, i = bid >> 3;
        const int logical = (x < rm ? x * (q + 1) : rm * (q + 1) + (x - rm) * q) + i;
        mt = logical / 6;
        nt = logical - mt * 6;
    } else {
        const int nwg = gridDim.x;
        const int cpx = nwg >> 3;
        const int logical = (bid & 7) * cpx + (bid >> 3);
        mt = logical / 6;
        nt = logical - mt * 6;
    }
    const int row0 = mt * BM;
    const int col0 = nt * BN;

    const int tid  = threadIdx.x;
    const int lane = tid & 63;
    const int wid  = tid >> 6;
    const int wm   = wid >> 1;
    const int wn   = wid & 1;

    const int srow = tid >> 2;          // 0..63
    const int sk   = (tid & 3) * 8;     // 0,8,16,24
    const bf16_t* a0 = Ab + (size_t)(row0 + srow) * PD + sk;
    const bf16_t* b0 = Wb + (size_t)(col0 + srow) * PD + sk;
    const int lds_lo = srow * BK + sk;
    const int lds_hi = (srow + 64) * BK + sk;

    f32x4 acc[4][4];
    #pragma unroll
    for (int i = 0; i < 4; ++i)
        #pragma unroll
        for (int j = 0; j < 4; ++j)
            acc[i][j] = f32x4{0.f, 0.f, 0.f, 0.f};

    const int lr = lane & 15;
    const int kg = lane >> 4;
    const int a_rd_off = (wm * 64 + lr) * BK + kg * 8;
    const int b_rd_off = (wn * 64 + lr) * BK + kg * 8;

    // prologue: stage tile 0 into buf 0
    gload16(a0,           Asb + lds_lo);
    gload16(a0 + 64 * PD, Asb + lds_hi);
    gload16(b0,           Bsb + lds_lo);
    gload16(b0 + 64 * PD, Bsb + lds_hi);
    __syncthreads();

    int cur = 0;
    for (int t = 0; t < NT; ++t) {
        if (t + 1 < NT) {
            const int k1 = (t + 1) * BK;
            const int nb = cur ^ 1;
            gload16(a0 + k1,           Asb + nb * (BM * BK) + lds_lo);
            gload16(a0 + 64 * PD + k1, Asb + nb * (BM * BK) + lds_hi);
            gload16(b0 + k1,           Bsb + nb * (BN * BK) + lds_lo);
            gload16(b0 + 64 * PD + k1, Bsb + nb * (BN * BK) + lds_hi);
        }

        bf16x8 af[4], bfv[4];
        #pragma unroll
        for (int i = 0; i < 4; ++i) {
            af[i]  = *(const bf16x8*)(Asb + cur * (BM * BK) + a_rd_off + i * 16 * BK);
            bfv[i] = *(const bf16x8*)(Bsb + cur * (BN * BK) + b_rd_off + i * 16 * BK);
        }
        #pragma unroll
        for (int i = 0; i < 4; ++i)
            #pragma unroll
            for (int j = 0; j < 4; ++j)
                acc[i][j] = __builtin_amdgcn_mfma_f32_16x16x32_bf16(
                    af[i], bfv[j], acc[i][j], 0, 0, 0);

        __syncthreads();
        cur ^= 1;
    }

    // ---- Epilogue: LDS-transposed, vectorized ----
    const int lrow_w  = wm * 16 + kg * 4;
    const int lcol_w  = wn * 64 + lr;
    const int rr = tid >> 3;                  // 0..31
    const int cg = tid & 7;                   // 0..7
    const int erow_local = (rr & 15) + (rr >> 4) * 64;

    #pragma unroll
    for (int mi = 0; mi < 4; ++mi) {
        if (mi) __syncthreads();
        #pragma unroll
        for (int r = 0; r < 4; ++r)
            #pragma unroll
            for (int ni = 0; ni < 4; ++ni)
                Cs[(lrow_w + r) * LDSC + lcol_w + ni * 16] = acc[mi][ni][r];
        __syncthreads();

        const int crow = row0 + mi * 16 + erow_local;
        if constexpr (USE_MAP) {
            if (crow >= Mc) continue;
            const int grow = rowmap[crow];
            int p0 = posids[2 * grow];
            int p1 = posids[2 * grow + 1];
            p0 = p0 < 0 ? 0 : p0;
            p1 = p1 < 0 ? 0 : p1;
            const float* t0 = ptab + (size_t)p0 * HID + col0;
            const float* t1 = ptab + (size_t)PSZ * HID + (size_t)p1 * HID + col0;
            float* orow = out + (size_t)grow * HID + col0;
            #pragma unroll
            for (int j = 0; j < 4; ++j) {
                const int c = (cg + 8 * j) * 4;
                float4 v  = *(const float4*)&Cs[rr * LDSC + c];
                const float4 e0 = *(const float4*)(t0 + c);
                const float4 e1 = *(const float4*)(t1 + c);
                v.x += e0.x + e1.x;
                v.y += e0.y + e1.y;
                v.z += e0.z + e1.z;
                v.w += e0.w + e1.w;
                *(float4*)(orow + c) = v;
            }
        } else {
            const int grow = crow;
            float* orow = out + (size_t)grow * HID + col0;
            const int mk = mask[grow];
            if (mk) {
                const float4 z{0.f, 0.f, 0.f, 0.f};
                #pragma unroll
                for (int j = 0; j < 4; ++j)
                    *(float4*)(orow + (cg + 8 * j) * 4) = z;
            } else {
                int p0 = posids[2 * grow];
                int p1 = posids[2 * grow + 1];
                p0 = p0 < 0 ? 0 : p0;
                p1 = p1 < 0 ? 0 : p1;
                const float* t0 = ptab + (size_t)p0 * HID + col0;
                const float* t1 = ptab + (size_t)PSZ * HID + (size_t)p1 * HID + col0;
                #pragma unroll
                for (int j = 0; j < 4; ++j) {
                    const int c = (cg + 8 * j) * 4;
                    float4 v  = *(const float4*)&Cs[rr * LDSC + c];
                    const float4 e0 = *(const float4*)(t0 + c);
                    const float4 e1 = *(const float4*)(t1 + c);
                    v.x += e0.x + e1.x;
                    v.y += e0.y + e1.y;
                    v.z += e0.z + e1.z;
                    v.w += e0.w + e1.w;
                    *(float4*)(orow + c) = v;
                }
            }
        }
    }
}

// ---------------- Fallback (fused kernel, used if ws too small) -------------
constexpr int LDSS = 40;

__global__ __launch_bounds__(256, 2)
void vpe_kernel(const float* __restrict__ pv,
                const int* __restrict__ posids,
                const int* __restrict__ mask,
                const float* __restrict__ W,
                const float* __restrict__ ptab,
                float* __restrict__ out)
{
    __shared__ alignas(16) bf16_t As[2][BM * LDSS];
    __shared__ alignas(16) bf16_t Bs[2][BM * LDSS];

    const int nwg = gridDim.x;
    const int cpx = nwg >> 3;
    const int logical = (blockIdx.x & 7) * cpx + (blockIdx.x >> 3);
    const int mt = logical / 6;
    const int nt = logical - mt * 6;
    const int row0 = mt * BM;
    const int col0 = nt * BN;

    const int tid  = threadIdx.x;
    const int lane = tid & 63;
    const int wid  = tid >> 6;
    const int wm   = wid >> 1;
    const int wn   = wid & 1;
    const int srow = tid >> 1;
    const int scol = (tid & 1) << 4;

    const float* aptr = pv + (size_t)(row0 + srow) * PD + scol;
    const float* bptr = W  + (size_t)(col0 + srow) * PD + scol;
    const int lds_w_off = srow * LDSS + scol;

    f32x4 acc[4][4];
    #pragma unroll
    for (int i = 0; i < 4; ++i)
        #pragma unroll
        for (int j = 0; j < 4; ++j)
            acc[i][j] = f32x4{0.f, 0.f, 0.f, 0.f};

    const int lr = lane & 15;
    const int kg = lane >> 4;
    const int a_rd_off = (wm * 64 + lr) * LDSS + kg * 8;
    const int b_rd_off = (wn * 64 + lr) * LDSS + kg * 8;

    float4 ra[4], rb[4];
    #pragma unroll
    for (int q = 0; q < 4; ++q) {
        ra[q] = *(const float4*)(aptr + q * 4);
        rb[q] = *(const float4*)(bptr + q * 4);
    }
    {
        bf16x8 av0 = cvt8_affine(ra[0], ra[1], 2.f, -1.f);
        bf16x8 av1 = cvt8_affine(ra[2], ra[3], 2.f, -1.f);
        bf16x8 bv0 = cvt8_affine(rb[0], rb[1], 1.f, 0.f);
        bf16x8 bv1 = cvt8_affine(rb[2], rb[3], 1.f, 0.f);
        *(bf16x8*)(&As[0][lds_w_off])     = av0;
        *(bf16x8*)(&As[0][lds_w_off] + 8) = av1;
        *(bf16x8*)(&Bs[0][lds_w_off])     = bv0;
        *(bf16x8*)(&Bs[0][lds_w_off] + 8) = bv1;
    }
    __syncthreads();

    int cur = 0;
    for (int t = 0; t < NT - 1; ++t) {
        const int k1 = (t + 1) * BK;
        #pragma unroll
        for (int q = 0; q < 4; ++q) {
            ra[q] = *(const float4*)(aptr + k1 + q * 4);
            rb[q] = *(const float4*)(bptr + k1 + q * 4);
        }
        bf16x8 af[4], bfv[4];
        #pragma unroll
        for (int i = 0; i < 4; ++i) {
            af[i]  = *(const bf16x8*)(&As[cur][a_rd_off] + i * 16 * LDSS);
            bfv[i] = *(const bf16x8*)(&Bs[cur][b_rd_off] + i * 16 * LDSS);
        }
        #pragma unroll
        for (int i = 0; i < 4; ++i)
            #pragma unroll
            for (int j = 0; j < 4; ++j)
                acc[i][j] = __builtin_amdgcn_mfma_f32_16x16x32_bf16(
                    af[i], bfv[j], acc[i][j], 0, 0, 0);
        {
            bf16x8 av0 = cvt8_affine(ra[0], ra[1], 2.f, -1.f);
            bf16x8 av1 = cvt8_affine(ra[2], ra[3], 2.f, -1.f);
            bf16x8 bv0 = cvt8_affine(rb[0], rb[1], 1.f, 0.f);
            bf16x8 bv1 = cvt8_affine(rb[2], rb[3], 1.f, 0.f);
            const int nb = cur ^ 1;
            *(bf16x8*)(&As[nb][lds_w_off])     = av0;
            *(bf16x8*)(&As[nb][lds_w_off] + 8) = av1;
            *(bf16x8*)(&Bs[nb][lds_w_off])     = bv0;
            *(bf16x8*)(&Bs[nb][lds_w_off] + 8) = bv1;
        }
        __syncthreads();
        cur ^= 1;
    }
    {
        bf16x8 af[4], bfv[4];
        #pragma unroll
        for (int i = 0; i < 4; ++i) {
            af[i]  = *(const bf16x8*)(&As[cur][a_rd_off] + i * 16 * LDSS);
            bfv[i] = *(const bf16x8*)(&Bs[cur][b_rd_off] + i * 16 * LDSS);
        }
        #pragma unroll
        for (int i = 0; i < 4; ++i)
            #pragma unroll
            for (int j = 0; j < 4; ++j)
                acc[i][j] = __builtin_amdgcn_mfma_f32_16x16x32_bf16(
                    af[i], bfv[j], acc[i][j], 0, 0, 0);
    }
    #pragma unroll
    for (int mi = 0; mi < 4; ++mi) {
        #pragma unroll
        for (int r = 0; r < 4; ++r) {
            const int grow = row0 + wm * 64 + mi * 16 + kg * 4 + r;
            const int mk = mask[grow];
            int p0 = posids[2 * grow];
            int p1 = posids[2 * grow + 1];
            p0 = p0 < 0 ? 0 : p0;
            p1 = p1 < 0 ? 0 : p1;
            const float* t0 = ptab + (size_t)p0 * HID;
            const float* t1 = ptab + (size_t)PSZ * HID + (size_t)p1 * HID;
            float* orow = out + (size_t)grow * HID;
            #pragma unroll
            for (int ni = 0; ni < 4; ++ni) {
                const int col = col0 + wn * 64 + ni * 16 + lr;
                const float v = acc[mi][ni][r] + t0[col] + t1[col];
                orow[col] = mk ? 0.f : v;
            }
        }
    }
}

extern "C" void kernel_launch(void* const* d_in, const int* in_sizes, int n_in,
                              void* d_out, int out_size, void* d_ws, size_t ws_size,
                              hipStream_t stream) {
    (void)in_sizes; (void)n_in; (void)out_size;
    const float* pv     = (const float*)d_in[0];
    const int*   posids = (const int*)d_in[1];
    const int*   mask   = (const int*)d_in[2];
    const float* W      = (const float*)d_in[3];
    const float* ptab   = (const float*)d_in[4];
    float*       out    = (float*)d_out;

    const size_t AB_B = PVN * sizeof(bf16_t);   // 96 MB
    const size_t WB_B = WN * sizeof(bf16_t);    // 1.125 MB
    const size_t RM_B = (size_t)MT * 4;         // 256 KB
    const size_t need1 = AB_B + WB_B;
    const size_t need2 = AB_B + WB_B + RM_B + 16;
    const int grid = (MT / BM) * (HID / BN);    // 3072

    if (ws_size >= need2) {
        bf16_t* Ab   = (bf16_t*)d_ws;
        bf16_t* Wb   = Ab + PVN;
        int* rowmap  = (int*)((char*)d_ws + AB_B + WB_B);
        int* counter = (int*)((char*)d_ws + AB_B + WB_B + RM_B);
        hipMemsetAsync(counter, 0, 16, stream);
        hipLaunchKernelGGL(compact_cvt, dim3(1088), dim3(256), 0, stream,
                           pv, mask, W, Ab, Wb, rowmap, counter, out);
        hipLaunchKernelGGL((gemm_kernel<true>), dim3(grid), dim3(256), 0, stream,
                           Ab, Wb, posids, mask, ptab, out, rowmap, counter);
    } else if (ws_size >= need1) {
        bf16_t* Ab = (bf16_t*)d_ws;
        bf16_t* Wb = Ab + PVN;
        hipLaunchKernelGGL(cvt_kernel, dim3(2048), dim3(256), 0, stream,
                           pv, W, Ab, Wb);
        hipLaunchKernelGGL((gemm_kernel<false>), dim3(grid), dim3(256), 0, stream,
                           Ab, Wb, posids, mask, ptab, out, nullptr, nullptr);
    } else {
        hipLaunchKernelGGL(vpe_kernel, dim3(grid), dim3(256), 0, stream,
                           pv, posids, mask, W, ptab, out);
    }
}